// Round 5
// baseline (573.542 us; speedup 1.0000x reference)
//
#include <hip/hip_runtime.h>
#include <hip/hip_bf16.h>

typedef short bf16x8 __attribute__((ext_vector_type(8)));
typedef float f32x4 __attribute__((ext_vector_type(4)));
typedef unsigned int u32;
typedef unsigned int u32x2 __attribute__((ext_vector_type(2)));

#define MFMA16 __builtin_amdgcn_mfma_f32_16x16x32_bf16
#define SCALE 0.17677669529663687f  // 1/sqrt(32)

// ws layout (bytes):
//   wqkv  bf16 [576][192]          @ 0        (221184)
//   wproj bf16 [192][192]          @ 221184   (73728)
//   biasar f32 [6][16][64][4]      @ 294912   (98304)
//   bq    f32  [576]               @ 393216   (2304)
//   Os    frag dump                @ 395520   (100663296)   [split path only]
#define OS_OFF 395520
#define WS_NEED (395520 + 100663296)

__device__ __forceinline__ unsigned short f2b(float x) {
  u32 u = __float_as_uint(x);
  u = (u + 0x7FFFu + ((u >> 16) & 1u)) >> 16;
  return (unsigned short)u;
}
__device__ __forceinline__ u32 pk2(float a, float b) {
  __hip_bfloat162 h = __float22bfloat162_rn(float2{a, b});
  return *(u32*)&h;
}
__device__ __forceinline__ uint2 pk4(f32x4 v) {
  return make_uint2(pk2(v[0], v[1]), pk2(v[2], v[3]));
}

// C-frag pair -> A/B-frag bf16x8 via 2x v_permlane16_swap (VALU). The k-dim
// carries a fixed permutation pi; pi is identical for every operand produced
// by this helper, so it cancels inside MFMA dot products.
__device__ __forceinline__ bf16x8 xpose(f32x4 a0, f32x4 a1) {
  u32 s0 = pk2(a0[0], a0[1]);
  u32 s1 = pk2(a0[2], a0[3]);
  u32 s2 = pk2(a1[0], a1[1]);
  u32 s3 = pk2(a1[2], a1[3]);
  u32x2 r0 = __builtin_amdgcn_permlane16_swap(s0, s2, false, false);
  u32x2 r1 = __builtin_amdgcn_permlane16_swap(s1, s3, false, false);
  union {
    u32 w[4];
    bf16x8 v;
  } u;
  u.w[0] = r0[0];
  u.w[1] = r1[0];
  u.w[2] = r0[1];
  u.w[3] = r1[1];
  return u.v;
}

__global__ void prep_kernel(const float* __restrict__ qkv_w, const float* __restrict__ qkv_b,
                            const float* __restrict__ proj_w, const float* __restrict__ rpb,
                            unsigned short* __restrict__ wqkv, unsigned short* __restrict__ wproj,
                            float* __restrict__ biasar, float* __restrict__ bq) {
  int i0 = blockIdx.x * blockDim.x + threadIdx.x;
  int stride = gridDim.x * blockDim.x;
  for (int i = i0; i < 576 * 192; i += stride) {
    float v = qkv_w[i];
    if (i < 192 * 192) v *= SCALE;  // q rows are f < 192
    wqkv[i] = f2b(v);
  }
  for (int i = i0; i < 192 * 192; i += stride) wproj[i] = f2b(proj_w[i]);
  for (int i = i0; i < 576; i += stride) {
    float v = qkv_b[i];
    if (i < 192) v *= SCALE;
    bq[i] = v;
  }
  for (int i = i0; i < 6 * 16 * 64 * 4; i += stride) {
    int r = i & 3;
    int lane = (i >> 2) & 63;
    int fid = (i >> 8) & 15;
    int h = i >> 12;
    int mt = fid >> 2, nt = fid & 3;
    int m = mt * 16 + (lane >> 4) * 4 + r;
    int n = nt * 16 + (lane & 15);
    int idx = ((n >> 3) - (m >> 3) + 7) * 15 + ((n & 7) - (m & 7) + 7);
    biasar[i] = rpb[idx * 6 + h];
  }
}

// ===================== SPLIT PATH =====================
// win_attn3: block = (window, head-group of 3), 3 waves, wave = one head.
// Ends by dumping O fragments (post-1/l) straight to global in frag-native
// layout: uint2[ ((b*6+head)*8 + dt*4+nt) * 64 + lane ]. No trailing barriers.
__global__ void __launch_bounds__(192, 4) win_attn3(
    const float* __restrict__ x, const unsigned short* __restrict__ wqkv,
    const float* __restrict__ biasar, const float* __restrict__ bq,
    unsigned short* __restrict__ osout) {
  __shared__ __align__(16) char smem[24576];
  const int bid = blockIdx.x;
  const int b = bid >> 1;
  const int hg = bid & 1;
  const int tid = threadIdx.x;
  const int w = tid >> 6;  // 0..2
  const int head = hg * 3 + w;
  const int lane = tid & 63;
  const int g = lane >> 4;
  const int c = lane & 15;
  char* xs = smem;

  // ---------- stage full x -> bf16 swizzled LDS ----------
  {
    const float* xb = x + (size_t)b * 12288;
#pragma unroll
    for (int it = 0; it < 16; ++it) {
      int idx = tid + it * 192;  // float4 index in [0,3072)
      int tok = idx / 48, c4 = idx % 48;
      float4 v = *(const float4*)(xb + tok * 192 + c4 * 4);
      *(uint2*)(xs + tok * 384 + (((c4 >> 1) ^ (tok & 7)) << 4) + (c4 & 1) * 8) =
          make_uint2(pk2(v.x, v.y), pk2(v.z, v.w));
    }
  }
  __syncthreads();

#define XFRAG(tt, kt) \
  (*(const bf16x8*)(xs + ((tt) * 16 + c) * 384 + ((((kt) * 4 + g) ^ (c & 7)) << 4)))

  // ---------- Q pass ----------
  bf16x8 qb[4];
  {
    f32x4 acc[2][4];
#pragma unroll
    for (int dt = 0; dt < 2; ++dt)
#pragma unroll
      for (int tt = 0; tt < 4; ++tt) acc[dt][tt] = (f32x4)0.0f;
#pragma unroll
    for (int kt = 0; kt < 6; ++kt) {
      bf16x8 wf[2];
#pragma unroll
      for (int dt = 0; dt < 2; ++dt)
        wf[dt] = *(const bf16x8*)(wqkv + (size_t)(head * 32 + dt * 16 + c) * 192 + kt * 32 + 8 * g);
#pragma unroll
      for (int tt = 0; tt < 4; ++tt) {
        bf16x8 xf = XFRAG(tt, kt);
#pragma unroll
        for (int dt = 0; dt < 2; ++dt) acc[dt][tt] = MFMA16(wf[dt], xf, acc[dt][tt], 0, 0, 0);
      }
    }
#pragma unroll
    for (int dt = 0; dt < 2; ++dt)
#pragma unroll
      for (int r = 0; r < 4; ++r) {
        float bv = bq[head * 32 + dt * 16 + 4 * g + r];
#pragma unroll
        for (int tt = 0; tt < 4; ++tt) acc[dt][tt][r] += bv;
      }
#pragma unroll
    for (int nt = 0; nt < 4; ++nt) qb[nt] = xpose(acc[0][nt], acc[1][nt]);
  }

  // ---------- K pass ----------
  bf16x8 ka[4];
  {
    f32x4 acc[2][4];
#pragma unroll
    for (int dt = 0; dt < 2; ++dt)
#pragma unroll
      for (int tt = 0; tt < 4; ++tt) acc[dt][tt] = (f32x4)0.0f;
#pragma unroll
    for (int kt = 0; kt < 6; ++kt) {
      bf16x8 wf[2];
#pragma unroll
      for (int dt = 0; dt < 2; ++dt)
        wf[dt] =
            *(const bf16x8*)(wqkv + (size_t)(192 + head * 32 + dt * 16 + c) * 192 + kt * 32 + 8 * g);
#pragma unroll
      for (int tt = 0; tt < 4; ++tt) {
        bf16x8 xf = XFRAG(tt, kt);
#pragma unroll
        for (int dt = 0; dt < 2; ++dt) acc[dt][tt] = MFMA16(wf[dt], xf, acc[dt][tt], 0, 0, 0);
      }
    }
#pragma unroll
    for (int dt = 0; dt < 2; ++dt)
#pragma unroll
      for (int r = 0; r < 4; ++r) {
        float bv = bq[192 + head * 32 + dt * 16 + 4 * g + r];
#pragma unroll
        for (int tt = 0; tt < 4; ++tt) acc[dt][tt][r] += bv;
      }
#pragma unroll
    for (int mt = 0; mt < 4; ++mt) ka[mt] = xpose(acc[0][mt], acc[1][mt]);
  }

  // ---------- S in two n-halves: bias, softmax, pack P frags ----------
  bf16x8 pbf[2][4];
  float linv[4];
  const f32x4* bias4 = (const f32x4*)biasar;
#pragma unroll
  for (int h = 0; h < 2; ++h) {
    f32x4 s[4][2];
#pragma unroll
    for (int mt = 0; mt < 4; ++mt)
#pragma unroll
      for (int n2 = 0; n2 < 2; ++n2) {
        int nt = h * 2 + n2;
        f32x4 t = MFMA16(ka[mt], qb[nt], (f32x4)0.0f, 0, 0, 0);
        s[mt][n2] = t + bias4[(head * 16 + mt * 4 + nt) * 64 + lane];
      }
#pragma unroll
    for (int n2 = 0; n2 < 2; ++n2) {
      int nt = h * 2 + n2;
      float mx = -1e30f;
#pragma unroll
      for (int mt = 0; mt < 4; ++mt)
#pragma unroll
        for (int r = 0; r < 4; ++r) mx = fmaxf(mx, s[mt][n2][r]);
      mx = fmaxf(mx, __shfl_xor(mx, 16));
      mx = fmaxf(mx, __shfl_xor(mx, 32));
      float sum = 0.0f;
#pragma unroll
      for (int mt = 0; mt < 4; ++mt)
#pragma unroll
        for (int r = 0; r < 4; ++r) {
          float e = __expf(s[mt][n2][r] - mx);
          s[mt][n2][r] = e;
          sum += e;
        }
      sum += __shfl_xor(sum, 16);
      sum += __shfl_xor(sum, 32);
      linv[nt] = 1.0f / sum;
    }
#pragma unroll
    for (int n2 = 0; n2 < 2; ++n2) {
      pbf[0][h * 2 + n2] = xpose(s[0][n2], s[1][n2]);
      pbf[1][h * 2 + n2] = xpose(s[2][n2], s[3][n2]);
    }
  }

  // ---------- V pass ----------
  bf16x8 va[2][2];
  {
    f32x4 acc[4][2];
#pragma unroll
    for (int mt = 0; mt < 4; ++mt)
#pragma unroll
      for (int dt = 0; dt < 2; ++dt) acc[mt][dt] = (f32x4)0.0f;
#pragma unroll
    for (int kt = 0; kt < 6; ++kt) {
      bf16x8 wf[2];
#pragma unroll
      for (int dt = 0; dt < 2; ++dt)
        wf[dt] =
            *(const bf16x8*)(wqkv + (size_t)(384 + head * 32 + dt * 16 + c) * 192 + kt * 32 + 8 * g);
#pragma unroll
      for (int tt = 0; tt < 4; ++tt) {
        bf16x8 xf = XFRAG(tt, kt);
#pragma unroll
        for (int dt = 0; dt < 2; ++dt) acc[tt][dt] = MFMA16(xf, wf[dt], acc[tt][dt], 0, 0, 0);
      }
    }
#pragma unroll
    for (int dt = 0; dt < 2; ++dt) {
      float bv = bq[384 + head * 32 + dt * 16 + c];
#pragma unroll
      for (int mt = 0; mt < 4; ++mt)
#pragma unroll
        for (int r = 0; r < 4; ++r) acc[mt][dt][r] += bv;
    }
#pragma unroll
    for (int dt = 0; dt < 2; ++dt)
#pragma unroll
      for (int kh = 0; kh < 2; ++kh) va[dt][kh] = xpose(acc[2 * kh][dt], acc[2 * kh + 1][dt]);
  }

  // ---------- O^T = V^T @ P^T ----------
  f32x4 o[2][4];
#pragma unroll
  for (int dt = 0; dt < 2; ++dt)
#pragma unroll
    for (int nt = 0; nt < 4; ++nt) o[dt][nt] = (f32x4)0.0f;
#pragma unroll
  for (int mh = 0; mh < 2; ++mh)
#pragma unroll
    for (int nt = 0; nt < 4; ++nt)
#pragma unroll
      for (int dt = 0; dt < 2; ++dt) o[dt][nt] = MFMA16(va[dt][mh], pbf[mh][nt], o[dt][nt], 0, 0, 0);

  // ---------- scale by 1/l and dump frags to global (coalesced uint2) ----------
  uint2* dst = (uint2*)osout + ((size_t)(b * 6 + head) * 8) * 64 + lane;
#pragma unroll
  for (int dt = 0; dt < 2; ++dt)
#pragma unroll
    for (int nt = 0; nt < 4; ++nt) {
#pragma unroll
      for (int r = 0; r < 4; ++r) o[dt][nt][r] *= linv[nt];
      dst[(dt * 4 + nt) * 64] = pk4(o[dt][nt]);
    }
}

// proj: block = 1 window (64 tokens), 4 waves; wave w covers f in [w*48, w*48+48).
// Stages the frag dump into [tok][384B] swizzled LDS, then GEMM vs wproj.
__global__ void __launch_bounds__(256, 4) proj_kernel(
    const unsigned short* __restrict__ osin, const unsigned short* __restrict__ wproj,
    const float* __restrict__ proj_b, float* __restrict__ out) {
  __shared__ __align__(16) char smem[24576];
  const int b = blockIdx.x;
  const int tid = threadIdx.x;
  const int w = tid >> 6;  // 0..3
  const int lane = tid & 63;
  const int g = lane >> 4;
  const int c = lane & 15;

  // ---------- decode frag dump -> [tok][c] swizzled LDS ----------
  {
    const uint2* src = (const uint2*)osin + (size_t)b * 3072;
#pragma unroll
    for (int it = 0; it < 12; ++it) {
      int i = tid + it * 256;
      int ls = i & 63;
      int frag = (i >> 6) & 7;  // dt*4 + nt
      int head = i >> 9;
      int tok = (frag & 3) * 16 + (ls & 15);
      int d0 = head * 32 + (frag >> 2) * 16 + 4 * (ls >> 4);
      uint2 v = src[i];
      *(uint2*)(smem + tok * 384 + ((((d0 >> 3)) ^ (tok & 7)) << 4) + (d0 & 7) * 2) = v;
    }
  }
  __syncthreads();

  // ---------- GEMM: out = Os @ wproj^T + b ----------
  f32x4 acc[4][3];
#pragma unroll
  for (int mt = 0; mt < 4; ++mt)
#pragma unroll
    for (int ft = 0; ft < 3; ++ft) acc[mt][ft] = (f32x4)0.0f;
#pragma unroll
  for (int kt = 0; kt < 6; ++kt) {
    bf16x8 wf[3];
#pragma unroll
    for (int ft = 0; ft < 3; ++ft)
      wf[ft] = *(const bf16x8*)(wproj + (size_t)(w * 48 + ft * 16 + c) * 192 + kt * 32 + 8 * g);
#pragma unroll
    for (int mt = 0; mt < 4; ++mt) {
      bf16x8 of = *(const bf16x8*)(smem + (mt * 16 + c) * 384 + (((kt * 4 + g) ^ (c & 7)) << 4));
#pragma unroll
      for (int ft = 0; ft < 3; ++ft) acc[mt][ft] = MFMA16(of, wf[ft], acc[mt][ft], 0, 0, 0);
    }
  }
  float* outb = out + (size_t)b * 12288;
#pragma unroll
  for (int ft = 0; ft < 3; ++ft) {
    float pbv = proj_b[w * 48 + ft * 16 + c];
#pragma unroll
    for (int mt = 0; mt < 4; ++mt)
#pragma unroll
      for (int r = 0; r < 4; ++r)
        outb[(mt * 16 + 4 * g + r) * 192 + w * 48 + ft * 16 + c] = acc[mt][ft][r] + pbv;
  }
}

// ===================== FUSED FALLBACK (R4, known-good 323us) =====================
__global__ void __launch_bounds__(384, 3) win_attn(
    const float* __restrict__ x, const unsigned short* __restrict__ wqkv,
    const unsigned short* __restrict__ wproj, const float* __restrict__ biasar,
    const float* __restrict__ bq, const float* __restrict__ proj_b, float* __restrict__ out) {
  __shared__ __align__(16) char smem[24576];
  const int b = blockIdx.x;
  const int tid = threadIdx.x;
  const int w = tid >> 6;
  const int lane = tid & 63;
  const int g = lane >> 4;
  const int c = lane & 15;
  char* xs = smem;

  {
    const float* xb = x + (size_t)b * 12288;
#pragma unroll
    for (int it = 0; it < 8; ++it) {
      int idx = tid + it * 384;
      int tok = idx / 48, c4 = idx % 48;
      float4 v = *(const float4*)(xb + tok * 192 + c4 * 4);
      *(uint2*)(xs + tok * 384 + (((c4 >> 1) ^ (tok & 7)) << 4) + (c4 & 1) * 8) =
          make_uint2(pk2(v.x, v.y), pk2(v.z, v.w));
    }
  }
  __syncthreads();

  bf16x8 qb[4];
  {
    f32x4 acc[2][4];
#pragma unroll
    for (int dt = 0; dt < 2; ++dt)
#pragma unroll
      for (int tt = 0; tt < 4; ++tt) acc[dt][tt] = (f32x4)0.0f;
#pragma unroll
    for (int kt = 0; kt < 6; ++kt) {
      bf16x8 wf[2];
#pragma unroll
      for (int dt = 0; dt < 2; ++dt)
        wf[dt] = *(const bf16x8*)(wqkv + (size_t)(w * 32 + dt * 16 + c) * 192 + kt * 32 + 8 * g);
#pragma unroll
      for (int tt = 0; tt < 4; ++tt) {
        bf16x8 xf = XFRAG(tt, kt);
#pragma unroll
        for (int dt = 0; dt < 2; ++dt) acc[dt][tt] = MFMA16(wf[dt], xf, acc[dt][tt], 0, 0, 0);
      }
    }
#pragma unroll
    for (int dt = 0; dt < 2; ++dt)
#pragma unroll
      for (int r = 0; r < 4; ++r) {
        float bv = bq[w * 32 + dt * 16 + 4 * g + r];
#pragma unroll
        for (int tt = 0; tt < 4; ++tt) acc[dt][tt][r] += bv;
      }
#pragma unroll
    for (int nt = 0; nt < 4; ++nt) qb[nt] = xpose(acc[0][nt], acc[1][nt]);
  }

  bf16x8 ka[4];
  {
    f32x4 acc[2][4];
#pragma unroll
    for (int dt = 0; dt < 2; ++dt)
#pragma unroll
      for (int tt = 0; tt < 4; ++tt) acc[dt][tt] = (f32x4)0.0f;
#pragma unroll
    for (int kt = 0; kt < 6; ++kt) {
      bf16x8 wf[2];
#pragma unroll
      for (int dt = 0; dt < 2; ++dt)
        wf[dt] =
            *(const bf16x8*)(wqkv + (size_t)(192 + w * 32 + dt * 16 + c) * 192 + kt * 32 + 8 * g);
#pragma unroll
      for (int tt = 0; tt < 4; ++tt) {
        bf16x8 xf = XFRAG(tt, kt);
#pragma unroll
        for (int dt = 0; dt < 2; ++dt) acc[dt][tt] = MFMA16(wf[dt], xf, acc[dt][tt], 0, 0, 0);
      }
    }
#pragma unroll
    for (int dt = 0; dt < 2; ++dt)
#pragma unroll
      for (int r = 0; r < 4; ++r) {
        float bv = bq[192 + w * 32 + dt * 16 + 4 * g + r];
#pragma unroll
        for (int tt = 0; tt < 4; ++tt) acc[dt][tt][r] += bv;
      }
#pragma unroll
    for (int mt = 0; mt < 4; ++mt) ka[mt] = xpose(acc[0][mt], acc[1][mt]);
  }

  bf16x8 pbf[2][4];
  float linv[4];
  const f32x4* bias4 = (const f32x4*)biasar;
#pragma unroll
  for (int h = 0; h < 2; ++h) {
    f32x4 s[4][2];
#pragma unroll
    for (int mt = 0; mt < 4; ++mt)
#pragma unroll
      for (int n2 = 0; n2 < 2; ++n2) {
        int nt = h * 2 + n2;
        f32x4 t = MFMA16(ka[mt], qb[nt], (f32x4)0.0f, 0, 0, 0);
        s[mt][n2] = t + bias4[(w * 16 + mt * 4 + nt) * 64 + lane];
      }
#pragma unroll
    for (int n2 = 0; n2 < 2; ++n2) {
      int nt = h * 2 + n2;
      float mx = -1e30f;
#pragma unroll
      for (int mt = 0; mt < 4; ++mt)
#pragma unroll
        for (int r = 0; r < 4; ++r) mx = fmaxf(mx, s[mt][n2][r]);
      mx = fmaxf(mx, __shfl_xor(mx, 16));
      mx = fmaxf(mx, __shfl_xor(mx, 32));
      float sum = 0.0f;
#pragma unroll
      for (int mt = 0; mt < 4; ++mt)
#pragma unroll
        for (int r = 0; r < 4; ++r) {
          float e = __expf(s[mt][n2][r] - mx);
          s[mt][n2][r] = e;
          sum += e;
        }
      sum += __shfl_xor(sum, 16);
      sum += __shfl_xor(sum, 32);
      linv[nt] = 1.0f / sum;
    }
#pragma unroll
    for (int n2 = 0; n2 < 2; ++n2) {
      pbf[0][h * 2 + n2] = xpose(s[0][n2], s[1][n2]);
      pbf[1][h * 2 + n2] = xpose(s[2][n2], s[3][n2]);
    }
  }

  bf16x8 va[2][2];
  {
    f32x4 acc[4][2];
#pragma unroll
    for (int mt = 0; mt < 4; ++mt)
#pragma unroll
      for (int dt = 0; dt < 2; ++dt) acc[mt][dt] = (f32x4)0.0f;
#pragma unroll
    for (int kt = 0; kt < 6; ++kt) {
      bf16x8 wf[2];
#pragma unroll
      for (int dt = 0; dt < 2; ++dt)
        wf[dt] =
            *(const bf16x8*)(wqkv + (size_t)(384 + w * 32 + dt * 16 + c) * 192 + kt * 32 + 8 * g);
#pragma unroll
      for (int tt = 0; tt < 4; ++tt) {
        bf16x8 xf = XFRAG(tt, kt);
#pragma unroll
        for (int dt = 0; dt < 2; ++dt) acc[tt][dt] = MFMA16(xf, wf[dt], acc[tt][dt], 0, 0, 0);
      }
    }
#pragma unroll
    for (int dt = 0; dt < 2; ++dt) {
      float bv = bq[384 + w * 32 + dt * 16 + c];
#pragma unroll
      for (int mt = 0; mt < 4; ++mt)
#pragma unroll
        for (int r = 0; r < 4; ++r) acc[mt][dt][r] += bv;
    }
#pragma unroll
    for (int dt = 0; dt < 2; ++dt)
#pragma unroll
      for (int kh = 0; kh < 2; ++kh) va[dt][kh] = xpose(acc[2 * kh][dt], acc[2 * kh + 1][dt]);
  }

  f32x4 o[2][4];
#pragma unroll
  for (int dt = 0; dt < 2; ++dt)
#pragma unroll
    for (int nt = 0; nt < 4; ++nt) o[dt][nt] = (f32x4)0.0f;
#pragma unroll
  for (int mh = 0; mh < 2; ++mh)
#pragma unroll
    for (int nt = 0; nt < 4; ++nt)
#pragma unroll
      for (int dt = 0; dt < 2; ++dt) o[dt][nt] = MFMA16(va[dt][mh], pbf[mh][nt], o[dt][nt], 0, 0, 0);
#pragma unroll
  for (int dt = 0; dt < 2; ++dt)
#pragma unroll
    for (int nt = 0; nt < 4; ++nt)
#pragma unroll
      for (int r = 0; r < 4; ++r) o[dt][nt][r] *= linv[nt];

  __syncthreads();
#pragma unroll
  for (int dt = 0; dt < 2; ++dt)
#pragma unroll
    for (int nt = 0; nt < 4; ++nt)
      *(uint2*)(xs + (nt * 16 + c) * 384 + (((w * 4 + dt * 2 + (g >> 1)) ^ (c & 7)) << 4) +
                (g & 1) * 8) =
          make_uint2(pk2(o[dt][nt][0], o[dt][nt][1]), pk2(o[dt][nt][2], o[dt][nt][3]));
  __syncthreads();

  f32x4 accP[4][2];
#pragma unroll
  for (int mt = 0; mt < 4; ++mt)
#pragma unroll
    for (int ft = 0; ft < 2; ++ft) accP[mt][ft] = (f32x4)0.0f;
#pragma unroll
  for (int kt = 0; kt < 6; ++kt) {
    bf16x8 wp[2];
#pragma unroll
    for (int ft = 0; ft < 2; ++ft)
      wp[ft] = *(const bf16x8*)(wproj + (size_t)(w * 32 + ft * 16 + c) * 192 + kt * 32 + 8 * g);
#pragma unroll
    for (int mt = 0; mt < 4; ++mt) {
      bf16x8 of = *(const bf16x8*)(xs + (mt * 16 + c) * 384 + (((kt * 4 + g) ^ (c & 7)) << 4));
#pragma unroll
      for (int ft = 0; ft < 2; ++ft) accP[mt][ft] = MFMA16(of, wp[ft], accP[mt][ft], 0, 0, 0);
    }
  }
  float pb0 = proj_b[w * 32 + c];
  float pb1 = proj_b[w * 32 + 16 + c];
  float* outb = out + (size_t)b * 12288;
#pragma unroll
  for (int mt = 0; mt < 4; ++mt)
#pragma unroll
    for (int ft = 0; ft < 2; ++ft) {
      float pbv = ft ? pb1 : pb0;
#pragma unroll
      for (int r = 0; r < 4; ++r)
        outb[(mt * 16 + 4 * g + r) * 192 + w * 32 + ft * 16 + c] = accP[mt][ft][r] + pbv;
    }
}

extern "C" void kernel_launch(void* const* d_in, const int* in_sizes, int n_in,
                              void* d_out, int out_size, void* d_ws, size_t ws_size,
                              hipStream_t stream) {
  const float* x = (const float*)d_in[0];
  const float* qkv_w = (const float*)d_in[1];
  const float* qkv_b = (const float*)d_in[2];
  const float* proj_w = (const float*)d_in[3];
  const float* proj_b = (const float*)d_in[4];
  const float* rpb = (const float*)d_in[5];
  char* ws = (char*)d_ws;
  unsigned short* wqkv = (unsigned short*)ws;
  unsigned short* wproj = (unsigned short*)(ws + 221184);
  float* biasar = (float*)(ws + 294912);
  float* bqv = (float*)(ws + 393216);

  prep_kernel<<<432, 256, 0, stream>>>(qkv_w, qkv_b, proj_w, rpb, wqkv, wproj, biasar, bqv);

  if (ws_size >= (size_t)WS_NEED) {
    unsigned short* osbuf = (unsigned short*)(ws + OS_OFF);
    win_attn3<<<8192, 192, 0, stream>>>(x, wqkv, biasar, bqv, osbuf);
    proj_kernel<<<4096, 256, 0, stream>>>(osbuf, wproj, proj_b, (float*)d_out);
  } else {
    win_attn<<<4096, 384, 0, stream>>>(x, wqkv, wproj, biasar, bqv, proj_b, (float*)d_out);
  }
}

// Round 6
// 380.122 us; speedup vs baseline: 1.5088x; 1.5088x over previous
//
#include <hip/hip_runtime.h>
#include <hip/hip_bf16.h>

typedef short bf16x8 __attribute__((ext_vector_type(8)));
typedef float f32x4 __attribute__((ext_vector_type(4)));
typedef unsigned int u32;
typedef unsigned int u32x2 __attribute__((ext_vector_type(2)));

#define MFMA16 __builtin_amdgcn_mfma_f32_16x16x32_bf16
#define SCALE 0.17677669529663687f  // 1/sqrt(32)

// ws layout (bytes):
//   wqkv  bf16 [576][192]          @ 0        (221184)
//   wproj bf16 [192][192]          @ 221184   (73728)
//   biasar f32 [6][16][64][4]      @ 294912   (98304)
//   bq    f32  [576]               @ 393216   (2304)
//   Os    frag dump                @ 395520   (100663296)   [split path only]
#define OS_OFF 395520
#define WS_NEED (395520 + 100663296)

__device__ __forceinline__ unsigned short f2b(float x) {
  u32 u = __float_as_uint(x);
  u = (u + 0x7FFFu + ((u >> 16) & 1u)) >> 16;
  return (unsigned short)u;
}
__device__ __forceinline__ u32 pk2(float a, float b) {
  __hip_bfloat162 h = __float22bfloat162_rn(float2{a, b});
  return *(u32*)&h;
}
__device__ __forceinline__ uint2 pk4(f32x4 v) {
  return make_uint2(pk2(v[0], v[1]), pk2(v[2], v[3]));
}

// C-frag pair -> A/B-frag bf16x8 via 2x v_permlane16_swap (VALU). The k-dim
// carries a fixed permutation pi; pi is identical for every operand produced
// by this helper, so it cancels inside MFMA dot products.
__device__ __forceinline__ bf16x8 xpose(f32x4 a0, f32x4 a1) {
  u32 s0 = pk2(a0[0], a0[1]);
  u32 s1 = pk2(a0[2], a0[3]);
  u32 s2 = pk2(a1[0], a1[1]);
  u32 s3 = pk2(a1[2], a1[3]);
  u32x2 r0 = __builtin_amdgcn_permlane16_swap(s0, s2, false, false);
  u32x2 r1 = __builtin_amdgcn_permlane16_swap(s1, s3, false, false);
  union {
    u32 w[4];
    bf16x8 v;
  } u;
  u.w[0] = r0[0];
  u.w[1] = r1[0];
  u.w[2] = r0[1];
  u.w[3] = r1[1];
  return u.v;
}

__global__ void prep_kernel(const float* __restrict__ qkv_w, const float* __restrict__ qkv_b,
                            const float* __restrict__ proj_w, const float* __restrict__ rpb,
                            unsigned short* __restrict__ wqkv, unsigned short* __restrict__ wproj,
                            float* __restrict__ biasar, float* __restrict__ bq) {
  int i0 = blockIdx.x * blockDim.x + threadIdx.x;
  int stride = gridDim.x * blockDim.x;
  for (int i = i0; i < 576 * 192; i += stride) {
    float v = qkv_w[i];
    if (i < 192 * 192) v *= SCALE;  // q rows are f < 192
    wqkv[i] = f2b(v);
  }
  for (int i = i0; i < 192 * 192; i += stride) wproj[i] = f2b(proj_w[i]);
  for (int i = i0; i < 576; i += stride) {
    float v = qkv_b[i];
    if (i < 192) v *= SCALE;
    bq[i] = v;
  }
  for (int i = i0; i < 6 * 16 * 64 * 4; i += stride) {
    int r = i & 3;
    int lane = (i >> 2) & 63;
    int fid = (i >> 8) & 15;
    int h = i >> 12;
    int mt = fid >> 2, nt = fid & 3;
    int m = mt * 16 + (lane >> 4) * 4 + r;
    int n = nt * 16 + (lane & 15);
    int idx = ((n >> 3) - (m >> 3) + 7) * 15 + ((n & 7) - (m & 7) + 7);
    biasar[i] = rpb[idx * 6 + h];
  }
}

// ===================== SPLIT PATH =====================
// win_attnh: wave = (head, q-half). Block = 3 waves (192 thr); 4 blocks/window.
// Each wave: Q for its 32 query tokens, full K and V (duplicated across the
// head's two half-waves), S (4x2 frags), softmax, PV; dumps O frags to global.
// Grid swizzled so a window's 4 blocks share an XCD (bid%8 assumed XCD id).
__global__ void __launch_bounds__(192, 4) win_attnh(
    const float* __restrict__ x, const unsigned short* __restrict__ wqkv,
    const float* __restrict__ biasar, const float* __restrict__ bq,
    unsigned short* __restrict__ osout) {
  __shared__ __align__(16) char smem[24576];
  const int bid = blockIdx.x;
  const int b = (bid >> 5) * 8 + (bid & 7);  // window
  const int part = (bid >> 3) & 3;           // 3 units of 12
  const int tid = threadIdx.x;
  const int wv = tid >> 6;  // 0..2
  const int unit = part * 3 + wv;
  const int head = unit >> 1;
  const int half = unit & 1;
  const int lane = tid & 63;
  const int g = lane >> 4;
  const int c = lane & 15;
  char* xs = smem;

  // ---------- stage full x -> bf16 swizzled LDS ----------
  {
    const float* xb = x + (size_t)b * 12288;
#pragma unroll
    for (int it = 0; it < 16; ++it) {
      int idx = tid + it * 192;  // float4 index in [0,3072)
      int tok = idx / 48, c4 = idx % 48;
      float4 v = *(const float4*)(xb + tok * 192 + c4 * 4);
      *(uint2*)(xs + tok * 384 + (((c4 >> 1) ^ (tok & 7)) << 4) + (c4 & 1) * 8) =
          make_uint2(pk2(v.x, v.y), pk2(v.z, v.w));
    }
  }
  __syncthreads();

#define XFRAG(tt, kt) \
  (*(const bf16x8*)(xs + ((tt) * 16 + c) * 384 + ((((kt) * 4 + g) ^ (c & 7)) << 4)))

  // ---------- Q pass (this wave's 32 query tokens only) ----------
  bf16x8 qb[2];
  {
    f32x4 acc[2][2];
#pragma unroll
    for (int dt = 0; dt < 2; ++dt)
#pragma unroll
      for (int t2 = 0; t2 < 2; ++t2) acc[dt][t2] = (f32x4)0.0f;
#pragma unroll
    for (int kt = 0; kt < 6; ++kt) {
      bf16x8 wf[2];
#pragma unroll
      for (int dt = 0; dt < 2; ++dt)
        wf[dt] = *(const bf16x8*)(wqkv + (size_t)(head * 32 + dt * 16 + c) * 192 + kt * 32 + 8 * g);
#pragma unroll
      for (int t2 = 0; t2 < 2; ++t2) {
        bf16x8 xf = XFRAG(half * 2 + t2, kt);
#pragma unroll
        for (int dt = 0; dt < 2; ++dt) acc[dt][t2] = MFMA16(wf[dt], xf, acc[dt][t2], 0, 0, 0);
      }
    }
#pragma unroll
    for (int dt = 0; dt < 2; ++dt)
#pragma unroll
      for (int r = 0; r < 4; ++r) {
        float bv = bq[head * 32 + dt * 16 + 4 * g + r];
#pragma unroll
        for (int t2 = 0; t2 < 2; ++t2) acc[dt][t2][r] += bv;
      }
#pragma unroll
    for (int t2 = 0; t2 < 2; ++t2) qb[t2] = xpose(acc[0][t2], acc[1][t2]);
  }

  // ---------- K pass (full 64 tokens) ----------
  bf16x8 ka[4];
  {
    f32x4 acc[2][4];
#pragma unroll
    for (int dt = 0; dt < 2; ++dt)
#pragma unroll
      for (int tt = 0; tt < 4; ++tt) acc[dt][tt] = (f32x4)0.0f;
#pragma unroll
    for (int kt = 0; kt < 6; ++kt) {
      bf16x8 wf[2];
#pragma unroll
      for (int dt = 0; dt < 2; ++dt)
        wf[dt] =
            *(const bf16x8*)(wqkv + (size_t)(192 + head * 32 + dt * 16 + c) * 192 + kt * 32 + 8 * g);
#pragma unroll
      for (int tt = 0; tt < 4; ++tt) {
        bf16x8 xf = XFRAG(tt, kt);
#pragma unroll
        for (int dt = 0; dt < 2; ++dt) acc[dt][tt] = MFMA16(wf[dt], xf, acc[dt][tt], 0, 0, 0);
      }
    }
#pragma unroll
    for (int dt = 0; dt < 2; ++dt)
#pragma unroll
      for (int r = 0; r < 4; ++r) {
        float bv = bq[192 + head * 32 + dt * 16 + 4 * g + r];
#pragma unroll
        for (int tt = 0; tt < 4; ++tt) acc[dt][tt][r] += bv;
      }
#pragma unroll
    for (int mt = 0; mt < 4; ++mt) ka[mt] = xpose(acc[0][mt], acc[1][mt]);
  }

  // ---------- S (4m x 2n frags), bias, softmax, P frags ----------
  bf16x8 pbf[2][2];
  float linv[2];
  {
    const f32x4* bias4 = (const f32x4*)biasar;
    f32x4 s[4][2];
#pragma unroll
    for (int mt = 0; mt < 4; ++mt)
#pragma unroll
      for (int n2 = 0; n2 < 2; ++n2) {
        f32x4 t = MFMA16(ka[mt], qb[n2], (f32x4)0.0f, 0, 0, 0);
        s[mt][n2] = t + bias4[(head * 16 + mt * 4 + half * 2 + n2) * 64 + lane];
      }
#pragma unroll
    for (int n2 = 0; n2 < 2; ++n2) {
      float mx = -1e30f;
#pragma unroll
      for (int mt = 0; mt < 4; ++mt)
#pragma unroll
        for (int r = 0; r < 4; ++r) mx = fmaxf(mx, s[mt][n2][r]);
      mx = fmaxf(mx, __shfl_xor(mx, 16));
      mx = fmaxf(mx, __shfl_xor(mx, 32));
      float sum = 0.0f;
#pragma unroll
      for (int mt = 0; mt < 4; ++mt)
#pragma unroll
        for (int r = 0; r < 4; ++r) {
          float e = __expf(s[mt][n2][r] - mx);
          s[mt][n2][r] = e;
          sum += e;
        }
      sum += __shfl_xor(sum, 16);
      sum += __shfl_xor(sum, 32);
      linv[n2] = 1.0f / sum;
    }
#pragma unroll
    for (int n2 = 0; n2 < 2; ++n2) {
      pbf[0][n2] = xpose(s[0][n2], s[1][n2]);
      pbf[1][n2] = xpose(s[2][n2], s[3][n2]);
    }
  }

  // ---------- V pass (full 64 tokens) ----------
  bf16x8 va[2][2];
  {
    f32x4 acc[4][2];
#pragma unroll
    for (int mt = 0; mt < 4; ++mt)
#pragma unroll
      for (int dt = 0; dt < 2; ++dt) acc[mt][dt] = (f32x4)0.0f;
#pragma unroll
    for (int kt = 0; kt < 6; ++kt) {
      bf16x8 wf[2];
#pragma unroll
      for (int dt = 0; dt < 2; ++dt)
        wf[dt] =
            *(const bf16x8*)(wqkv + (size_t)(384 + head * 32 + dt * 16 + c) * 192 + kt * 32 + 8 * g);
#pragma unroll
      for (int tt = 0; tt < 4; ++tt) {
        bf16x8 xf = XFRAG(tt, kt);
#pragma unroll
        for (int dt = 0; dt < 2; ++dt) acc[tt][dt] = MFMA16(xf, wf[dt], acc[tt][dt], 0, 0, 0);
      }
    }
#pragma unroll
    for (int dt = 0; dt < 2; ++dt) {
      float bv = bq[384 + head * 32 + dt * 16 + c];
#pragma unroll
      for (int mt = 0; mt < 4; ++mt)
#pragma unroll
        for (int r = 0; r < 4; ++r) acc[mt][dt][r] += bv;
    }
#pragma unroll
    for (int dt = 0; dt < 2; ++dt)
#pragma unroll
      for (int kh = 0; kh < 2; ++kh) va[dt][kh] = xpose(acc[2 * kh][dt], acc[2 * kh + 1][dt]);
  }

  // ---------- O^T = V^T @ P^T, scale, dump ----------
  f32x4 o[2][2];
#pragma unroll
  for (int dt = 0; dt < 2; ++dt)
#pragma unroll
    for (int n2 = 0; n2 < 2; ++n2) o[dt][n2] = (f32x4)0.0f;
#pragma unroll
  for (int mh = 0; mh < 2; ++mh)
#pragma unroll
    for (int n2 = 0; n2 < 2; ++n2)
#pragma unroll
      for (int dt = 0; dt < 2; ++dt) o[dt][n2] = MFMA16(va[dt][mh], pbf[mh][n2], o[dt][n2], 0, 0, 0);

  uint2* dst = (uint2*)osout + ((size_t)((b * 6 + head) * 2 + half) * 4) * 64 + lane;
#pragma unroll
  for (int dt = 0; dt < 2; ++dt)
#pragma unroll
    for (int n2 = 0; n2 < 2; ++n2) {
#pragma unroll
      for (int r = 0; r < 4; ++r) o[dt][n2][r] *= linv[n2];
      dst[(dt * 2 + n2) * 64] = pk4(o[dt][n2]);
    }
}

// proj: block = 1 window (64 tokens), 4 waves; wave w covers f in [w*48, w*48+48).
// Stages the frag dump into [tok][384B] swizzled LDS, then GEMM vs wproj.
__global__ void __launch_bounds__(256, 4) proj_kernel(
    const unsigned short* __restrict__ osin, const unsigned short* __restrict__ wproj,
    const float* __restrict__ proj_b, float* __restrict__ out) {
  __shared__ __align__(16) char smem[24576];
  const int b = blockIdx.x;
  const int tid = threadIdx.x;
  const int w = tid >> 6;  // 0..3
  const int lane = tid & 63;
  const int g = lane >> 4;
  const int c = lane & 15;

  // ---------- decode frag dump -> [tok][d] swizzled LDS ----------
  {
    const uint2* src = (const uint2*)osin + (size_t)b * 3072;
#pragma unroll
    for (int it = 0; it < 12; ++it) {
      int i = tid + it * 256;
      int ls = i & 63;
      int f = (i >> 6) & 3;  // dt*2 + n2
      int unit = i >> 8;     // head*2 + half
      int head = unit >> 1, half = unit & 1;
      int dt = f >> 1, n2 = f & 1;
      int tok = half * 32 + n2 * 16 + (ls & 15);
      int d0 = head * 32 + dt * 16 + 4 * (ls >> 4);
      uint2 v = src[i];
      *(uint2*)(smem + tok * 384 + (((d0 >> 3) ^ (tok & 7)) << 4) + (d0 & 7) * 2) = v;
    }
  }
  __syncthreads();

  // ---------- GEMM: out = Os @ wproj^T + b ----------
  f32x4 acc[4][3];
#pragma unroll
  for (int mt = 0; mt < 4; ++mt)
#pragma unroll
    for (int ft = 0; ft < 3; ++ft) acc[mt][ft] = (f32x4)0.0f;
#pragma unroll
  for (int kt = 0; kt < 6; ++kt) {
    bf16x8 wf[3];
#pragma unroll
    for (int ft = 0; ft < 3; ++ft)
      wf[ft] = *(const bf16x8*)(wproj + (size_t)(w * 48 + ft * 16 + c) * 192 + kt * 32 + 8 * g);
#pragma unroll
    for (int mt = 0; mt < 4; ++mt) {
      bf16x8 of = *(const bf16x8*)(smem + (mt * 16 + c) * 384 + (((kt * 4 + g) ^ (c & 7)) << 4));
#pragma unroll
      for (int ft = 0; ft < 3; ++ft) acc[mt][ft] = MFMA16(of, wf[ft], acc[mt][ft], 0, 0, 0);
    }
  }
  float* outb = out + (size_t)b * 12288;
#pragma unroll
  for (int ft = 0; ft < 3; ++ft) {
    float pbv = proj_b[w * 48 + ft * 16 + c];
#pragma unroll
    for (int mt = 0; mt < 4; ++mt)
#pragma unroll
      for (int r = 0; r < 4; ++r)
        outb[(mt * 16 + 4 * g + r) * 192 + w * 48 + ft * 16 + c] = acc[mt][ft][r] + pbv;
  }
}

// ===================== FUSED FALLBACK (R4, known-good 323us) =====================
__global__ void __launch_bounds__(384, 3) win_attn(
    const float* __restrict__ x, const unsigned short* __restrict__ wqkv,
    const unsigned short* __restrict__ wproj, const float* __restrict__ biasar,
    const float* __restrict__ bq, const float* __restrict__ proj_b, float* __restrict__ out) {
  __shared__ __align__(16) char smem[24576];
  const int b = blockIdx.x;
  const int tid = threadIdx.x;
  const int w = tid >> 6;
  const int lane = tid & 63;
  const int g = lane >> 4;
  const int c = lane & 15;
  char* xs = smem;

  {
    const float* xb = x + (size_t)b * 12288;
#pragma unroll
    for (int it = 0; it < 8; ++it) {
      int idx = tid + it * 384;
      int tok = idx / 48, c4 = idx % 48;
      float4 v = *(const float4*)(xb + tok * 192 + c4 * 4);
      *(uint2*)(xs + tok * 384 + (((c4 >> 1) ^ (tok & 7)) << 4) + (c4 & 1) * 8) =
          make_uint2(pk2(v.x, v.y), pk2(v.z, v.w));
    }
  }
  __syncthreads();

  bf16x8 qb[4];
  {
    f32x4 acc[2][4];
#pragma unroll
    for (int dt = 0; dt < 2; ++dt)
#pragma unroll
      for (int tt = 0; tt < 4; ++tt) acc[dt][tt] = (f32x4)0.0f;
#pragma unroll
    for (int kt = 0; kt < 6; ++kt) {
      bf16x8 wf[2];
#pragma unroll
      for (int dt = 0; dt < 2; ++dt)
        wf[dt] = *(const bf16x8*)(wqkv + (size_t)(w * 32 + dt * 16 + c) * 192 + kt * 32 + 8 * g);
#pragma unroll
      for (int tt = 0; tt < 4; ++tt) {
        bf16x8 xf = XFRAG(tt, kt);
#pragma unroll
        for (int dt = 0; dt < 2; ++dt) acc[dt][tt] = MFMA16(wf[dt], xf, acc[dt][tt], 0, 0, 0);
      }
    }
#pragma unroll
    for (int dt = 0; dt < 2; ++dt)
#pragma unroll
      for (int r = 0; r < 4; ++r) {
        float bv = bq[w * 32 + dt * 16 + 4 * g + r];
#pragma unroll
        for (int tt = 0; tt < 4; ++tt) acc[dt][tt][r] += bv;
      }
#pragma unroll
    for (int nt = 0; nt < 4; ++nt) qb[nt] = xpose(acc[0][nt], acc[1][nt]);
  }

  bf16x8 ka[4];
  {
    f32x4 acc[2][4];
#pragma unroll
    for (int dt = 0; dt < 2; ++dt)
#pragma unroll
      for (int tt = 0; tt < 4; ++tt) acc[dt][tt] = (f32x4)0.0f;
#pragma unroll
    for (int kt = 0; kt < 6; ++kt) {
      bf16x8 wf[2];
#pragma unroll
      for (int dt = 0; dt < 2; ++dt)
        wf[dt] =
            *(const bf16x8*)(wqkv + (size_t)(192 + w * 32 + dt * 16 + c) * 192 + kt * 32 + 8 * g);
#pragma unroll
      for (int tt = 0; tt < 4; ++tt) {
        bf16x8 xf = XFRAG(tt, kt);
#pragma unroll
        for (int dt = 0; dt < 2; ++dt) acc[dt][tt] = MFMA16(wf[dt], xf, acc[dt][tt], 0, 0, 0);
      }
    }
#pragma unroll
    for (int dt = 0; dt < 2; ++dt)
#pragma unroll
      for (int r = 0; r < 4; ++r) {
        float bv = bq[192 + w * 32 + dt * 16 + 4 * g + r];
#pragma unroll
        for (int tt = 0; tt < 4; ++tt) acc[dt][tt][r] += bv;
      }
#pragma unroll
    for (int mt = 0; mt < 4; ++mt) ka[mt] = xpose(acc[0][mt], acc[1][mt]);
  }

  bf16x8 pbf[2][4];
  float linv[4];
  const f32x4* bias4 = (const f32x4*)biasar;
#pragma unroll
  for (int h = 0; h < 2; ++h) {
    f32x4 s[4][2];
#pragma unroll
    for (int mt = 0; mt < 4; ++mt)
#pragma unroll
      for (int n2 = 0; n2 < 2; ++n2) {
        int nt = h * 2 + n2;
        f32x4 t = MFMA16(ka[mt], qb[nt], (f32x4)0.0f, 0, 0, 0);
        s[mt][n2] = t + bias4[(w * 16 + mt * 4 + nt) * 64 + lane];
      }
#pragma unroll
    for (int n2 = 0; n2 < 2; ++n2) {
      int nt = h * 2 + n2;
      float mx = -1e30f;
#pragma unroll
      for (int mt = 0; mt < 4; ++mt)
#pragma unroll
        for (int r = 0; r < 4; ++r) mx = fmaxf(mx, s[mt][n2][r]);
      mx = fmaxf(mx, __shfl_xor(mx, 16));
      mx = fmaxf(mx, __shfl_xor(mx, 32));
      float sum = 0.0f;
#pragma unroll
      for (int mt = 0; mt < 4; ++mt)
#pragma unroll
        for (int r = 0; r < 4; ++r) {
          float e = __expf(s[mt][n2][r] - mx);
          s[mt][n2][r] = e;
          sum += e;
        }
      sum += __shfl_xor(sum, 16);
      sum += __shfl_xor(sum, 32);
      linv[nt] = 1.0f / sum;
    }
#pragma unroll
    for (int n2 = 0; n2 < 2; ++n2) {
      pbf[0][h * 2 + n2] = xpose(s[0][n2], s[1][n2]);
      pbf[1][h * 2 + n2] = xpose(s[2][n2], s[3][n2]);
    }
  }

  bf16x8 va[2][2];
  {
    f32x4 acc[4][2];
#pragma unroll
    for (int mt = 0; mt < 4; ++mt)
#pragma unroll
      for (int dt = 0; dt < 2; ++dt) acc[mt][dt] = (f32x4)0.0f;
#pragma unroll
    for (int kt = 0; kt < 6; ++kt) {
      bf16x8 wf[2];
#pragma unroll
      for (int dt = 0; dt < 2; ++dt)
        wf[dt] =
            *(const bf16x8*)(wqkv + (size_t)(384 + w * 32 + dt * 16 + c) * 192 + kt * 32 + 8 * g);
#pragma unroll
      for (int tt = 0; tt < 4; ++tt) {
        bf16x8 xf = XFRAG(tt, kt);
#pragma unroll
        for (int dt = 0; dt < 2; ++dt) acc[tt][dt] = MFMA16(xf, wf[dt], acc[tt][dt], 0, 0, 0);
      }
    }
#pragma unroll
    for (int dt = 0; dt < 2; ++dt) {
      float bv = bq[384 + w * 32 + dt * 16 + c];
#pragma unroll
      for (int mt = 0; mt < 4; ++mt)
#pragma unroll
        for (int r = 0; r < 4; ++r) acc[mt][dt][r] += bv;
    }
#pragma unroll
    for (int dt = 0; dt < 2; ++dt)
#pragma unroll
      for (int kh = 0; kh < 2; ++kh) va[dt][kh] = xpose(acc[2 * kh][dt], acc[2 * kh + 1][dt]);
  }

  f32x4 o[2][4];
#pragma unroll
  for (int dt = 0; dt < 2; ++dt)
#pragma unroll
    for (int nt = 0; nt < 4; ++nt) o[dt][nt] = (f32x4)0.0f;
#pragma unroll
  for (int mh = 0; mh < 2; ++mh)
#pragma unroll
    for (int nt = 0; nt < 4; ++nt)
#pragma unroll
      for (int dt = 0; dt < 2; ++dt) o[dt][nt] = MFMA16(va[dt][mh], pbf[mh][nt], o[dt][nt], 0, 0, 0);
#pragma unroll
  for (int dt = 0; dt < 2; ++dt)
#pragma unroll
    for (int nt = 0; nt < 4; ++nt)
#pragma unroll
      for (int r = 0; r < 4; ++r) o[dt][nt][r] *= linv[nt];

  __syncthreads();
#pragma unroll
  for (int dt = 0; dt < 2; ++dt)
#pragma unroll
    for (int nt = 0; nt < 4; ++nt)
      *(uint2*)(xs + (nt * 16 + c) * 384 + (((w * 4 + dt * 2 + (g >> 1)) ^ (c & 7)) << 4) +
                (g & 1) * 8) =
          make_uint2(pk2(o[dt][nt][0], o[dt][nt][1]), pk2(o[dt][nt][2], o[dt][nt][3]));
  __syncthreads();

  f32x4 accP[4][2];
#pragma unroll
  for (int mt = 0; mt < 4; ++mt)
#pragma unroll
    for (int ft = 0; ft < 2; ++ft) accP[mt][ft] = (f32x4)0.0f;
#pragma unroll
  for (int kt = 0; kt < 6; ++kt) {
    bf16x8 wp[2];
#pragma unroll
    for (int ft = 0; ft < 2; ++ft)
      wp[ft] = *(const bf16x8*)(wproj + (size_t)(w * 32 + ft * 16 + c) * 192 + kt * 32 + 8 * g);
#pragma unroll
    for (int mt = 0; mt < 4; ++mt) {
      bf16x8 of = *(const bf16x8*)(xs + (mt * 16 + c) * 384 + (((kt * 4 + g) ^ (c & 7)) << 4));
#pragma unroll
      for (int ft = 0; ft < 2; ++ft) accP[mt][ft] = MFMA16(of, wp[ft], accP[mt][ft], 0, 0, 0);
    }
  }
  float pb0 = proj_b[w * 32 + c];
  float pb1 = proj_b[w * 32 + 16 + c];
  float* outb = out + (size_t)b * 12288;
#pragma unroll
  for (int mt = 0; mt < 4; ++mt)
#pragma unroll
    for (int ft = 0; ft < 2; ++ft) {
      float pbv = ft ? pb1 : pb0;
#pragma unroll
      for (int r = 0; r < 4; ++r)
        outb[(mt * 16 + 4 * g + r) * 192 + w * 32 + ft * 16 + c] = accP[mt][ft][r] + pbv;
    }
}

extern "C" void kernel_launch(void* const* d_in, const int* in_sizes, int n_in,
                              void* d_out, int out_size, void* d_ws, size_t ws_size,
                              hipStream_t stream) {
  const float* x = (const float*)d_in[0];
  const float* qkv_w = (const float*)d_in[1];
  const float* qkv_b = (const float*)d_in[2];
  const float* proj_w = (const float*)d_in[3];
  const float* proj_b = (const float*)d_in[4];
  const float* rpb = (const float*)d_in[5];
  char* ws = (char*)d_ws;
  unsigned short* wqkv = (unsigned short*)ws;
  unsigned short* wproj = (unsigned short*)(ws + 221184);
  float* biasar = (float*)(ws + 294912);
  float* bqv = (float*)(ws + 393216);

  prep_kernel<<<432, 256, 0, stream>>>(qkv_w, qkv_b, proj_w, rpb, wqkv, wproj, biasar, bqv);

  if (ws_size >= (size_t)WS_NEED) {
    unsigned short* osbuf = (unsigned short*)(ws + OS_OFF);
    win_attnh<<<16384, 192, 0, stream>>>(x, wqkv, biasar, bqv, osbuf);
    proj_kernel<<<4096, 256, 0, stream>>>(osbuf, wproj, proj_b, (float*)d_out);
  } else {
    win_attn<<<4096, 384, 0, stream>>>(x, wqkv, wproj, biasar, bqv, proj_b, (float*)d_out);
  }
}

// Round 7
// 317.137 us; speedup vs baseline: 1.8085x; 1.1986x over previous
//
#include <hip/hip_runtime.h>
#include <hip/hip_bf16.h>

typedef short bf16x8 __attribute__((ext_vector_type(8)));
typedef float f32x4 __attribute__((ext_vector_type(4)));
typedef unsigned int u32;
typedef unsigned int u32x2 __attribute__((ext_vector_type(2)));

#define MFMA16 __builtin_amdgcn_mfma_f32_16x16x32_bf16
#define SCALE 0.17677669529663687f  // 1/sqrt(32)

// ws layout (bytes):
//   wqkv  bf16 [576][192]          @ 0        (221184)
//   wproj bf16 [192][192]          @ 221184   (73728)
//   biasar f32 [6][16][64][4]      @ 294912   (98304)
//   bq    f32  [576]               @ 393216   (2304)
//   Os    frag dump                @ 395520   (100663296)   [split path only]
#define OS_OFF 395520
#define WS_NEED (395520 + 100663296)

__device__ __forceinline__ unsigned short f2b(float x) {
  u32 u = __float_as_uint(x);
  u = (u + 0x7FFFu + ((u >> 16) & 1u)) >> 16;
  return (unsigned short)u;
}
__device__ __forceinline__ u32 pk2(float a, float b) {
  __hip_bfloat162 h = __float22bfloat162_rn(float2{a, b});
  return *(u32*)&h;
}
__device__ __forceinline__ uint2 pk4(f32x4 v) {
  return make_uint2(pk2(v[0], v[1]), pk2(v[2], v[3]));
}

// C-frag pair -> A/B-frag bf16x8 via 2x v_permlane16_swap (VALU). The k-dim
// carries a fixed permutation pi; pi is identical for every operand produced
// by this helper, so it cancels inside MFMA dot products.
__device__ __forceinline__ bf16x8 xpose(f32x4 a0, f32x4 a1) {
  u32 s0 = pk2(a0[0], a0[1]);
  u32 s1 = pk2(a0[2], a0[3]);
  u32 s2 = pk2(a1[0], a1[1]);
  u32 s3 = pk2(a1[2], a1[3]);
  u32x2 r0 = __builtin_amdgcn_permlane16_swap(s0, s2, false, false);
  u32x2 r1 = __builtin_amdgcn_permlane16_swap(s1, s3, false, false);
  union {
    u32 w[4];
    bf16x8 v;
  } u;
  u.w[0] = r0[0];
  u.w[1] = r1[0];
  u.w[2] = r0[1];
  u.w[3] = r1[1];
  return u.v;
}

__global__ void prep_kernel(const float* __restrict__ qkv_w, const float* __restrict__ qkv_b,
                            const float* __restrict__ proj_w, const float* __restrict__ rpb,
                            unsigned short* __restrict__ wqkv, unsigned short* __restrict__ wproj,
                            float* __restrict__ biasar, float* __restrict__ bq) {
  int i0 = blockIdx.x * blockDim.x + threadIdx.x;
  int stride = gridDim.x * blockDim.x;
  for (int i = i0; i < 576 * 192; i += stride) {
    float v = qkv_w[i];
    if (i < 192 * 192) v *= SCALE;  // q rows are f < 192
    wqkv[i] = f2b(v);
  }
  for (int i = i0; i < 192 * 192; i += stride) wproj[i] = f2b(proj_w[i]);
  for (int i = i0; i < 576; i += stride) {
    float v = qkv_b[i];
    if (i < 192) v *= SCALE;
    bq[i] = v;
  }
  for (int i = i0; i < 6 * 16 * 64 * 4; i += stride) {
    int r = i & 3;
    int lane = (i >> 2) & 63;
    int fid = (i >> 8) & 15;
    int h = i >> 12;
    int mt = fid >> 2, nt = fid & 3;
    int m = mt * 16 + (lane >> 4) * 4 + r;
    int n = nt * 16 + (lane & 15);
    int idx = ((n >> 3) - (m >> 3) + 7) * 15 + ((n & 7) - (m & 7) + 7);
    biasar[i] = rpb[idx * 6 + h];
  }
}

// ===================== SPLIT PATH =====================
// win_attn6: block = (window, head-group of 3) = 6 waves; wave = (head, q-half).
// half0 computes K, half1 computes V; frags exchanged via LDS (no duplicate
// K/V MFMA work). Bias folded into MFMA C operands. LDS x tile rows padded to
// 400B so all ds/global addresses are per-lane base + immediate offset.
// LDS: [0,25600) x bf16 [64 tok][400B rows]; [25600,50176) exchange (3 heads x 8KB).
__global__ void __launch_bounds__(384, 4) win_attn6(
    const float* __restrict__ x, const unsigned short* __restrict__ wqkv,
    const float* __restrict__ biasar, const float* __restrict__ bq,
    unsigned short* __restrict__ osout) {
  __shared__ __align__(16) char smem[50176];
  const int bid = blockIdx.x;
  const int b = bid >> 1;   // window
  const int hg = bid & 1;   // head group
  const int tid = threadIdx.x;
  const int wv = tid >> 6;       // 0..5
  const int hl = wv >> 1;        // head within block 0..2
  const int head = hg * 3 + hl;  // global head
  const int half = wv & 1;       // q-half
  const int lane = tid & 63;
  const int g = lane >> 4;
  const int c = lane & 15;
  char* xs = smem;
  char* exch = smem + 25600;

  // ---------- stage full x -> bf16 LDS, rows padded to 400B ----------
  {
    const float4* src = (const float4*)(x + (size_t)b * 12288) + tid;
    char* wdst = xs + (tid / 48) * 400 + (tid % 48) * 8;
#pragma unroll
    for (int it = 0; it < 8; ++it) {
      float4 v = src[it * 384];
      *(uint2*)(wdst + it * 3200) = make_uint2(pk2(v.x, v.y), pk2(v.z, v.w));
    }
  }
  __syncthreads();

  const char* xr = xs + c * 400 + g * 16;
#define XF(tt, kt) (*(const bf16x8*)(xr + (tt) * 6400 + (kt) * 64))

  // ---------- Q pass (this wave's 32 query tokens; bias as C-init) ----------
  bf16x8 qb[2];
  {
    const unsigned short* wq0 = wqkv + (size_t)(head * 32 + c) * 192 + 8 * g;
    const unsigned short* wq1 = wq0 + 16 * 192;
    f32x4 bq0 = *(const f32x4*)(bq + head * 32 + 4 * g);
    f32x4 bq1 = *(const f32x4*)(bq + head * 32 + 16 + 4 * g);
    f32x4 a00 = bq0, a01 = bq0, a10 = bq1, a11 = bq1;
#pragma unroll
    for (int kt = 0; kt < 6; ++kt) {
      bf16x8 w0 = *(const bf16x8*)(wq0 + kt * 32);
      bf16x8 w1 = *(const bf16x8*)(wq1 + kt * 32);
      bf16x8 x0 = XF(half * 2 + 0, kt);
      bf16x8 x1 = XF(half * 2 + 1, kt);
      a00 = MFMA16(w0, x0, a00, 0, 0, 0);
      a10 = MFMA16(w1, x0, a10, 0, 0, 0);
      a01 = MFMA16(w0, x1, a01, 0, 0, 0);
      a11 = MFMA16(w1, x1, a11, 0, 0, 0);
    }
    qb[0] = xpose(a00, a10);
    qb[1] = xpose(a01, a11);
  }

  // ---------- K xor V pass (wave-uniform branch), then exchange ----------
  bf16x8 ka[4], va[2][2];
  {
    char* ew = exch + hl * 8192 + half * 4096 + lane * 16;
    if (half == 0) {
      const unsigned short* wk0 = wqkv + (size_t)(192 + head * 32 + c) * 192 + 8 * g;
      const unsigned short* wk1 = wk0 + 16 * 192;
      f32x4 bk0 = *(const f32x4*)(bq + 192 + head * 32 + 4 * g);
      f32x4 bk1 = *(const f32x4*)(bq + 192 + head * 32 + 16 + 4 * g);
      f32x4 acc[2][4];
#pragma unroll
      for (int tt = 0; tt < 4; ++tt) {
        acc[0][tt] = bk0;
        acc[1][tt] = bk1;
      }
#pragma unroll
      for (int kt = 0; kt < 6; ++kt) {
        bf16x8 w0 = *(const bf16x8*)(wk0 + kt * 32);
        bf16x8 w1 = *(const bf16x8*)(wk1 + kt * 32);
#pragma unroll
        for (int tt = 0; tt < 4; ++tt) {
          bf16x8 xf = XF(tt, kt);
          acc[0][tt] = MFMA16(w0, xf, acc[0][tt], 0, 0, 0);
          acc[1][tt] = MFMA16(w1, xf, acc[1][tt], 0, 0, 0);
        }
      }
#pragma unroll
      for (int mt = 0; mt < 4; ++mt) {
        ka[mt] = xpose(acc[0][mt], acc[1][mt]);
        *(bf16x8*)(ew + mt * 1024) = ka[mt];
      }
    } else {
      const unsigned short* wv0 = wqkv + (size_t)(384 + head * 32 + c) * 192 + 8 * g;
      const unsigned short* wv1 = wv0 + 16 * 192;
      float bv0 = bq[384 + head * 32 + c];
      float bv1 = bq[384 + head * 32 + 16 + c];
      f32x4 acc[4][2];
#pragma unroll
      for (int tt = 0; tt < 4; ++tt) {
        acc[tt][0] = f32x4{bv0, bv0, bv0, bv0};
        acc[tt][1] = f32x4{bv1, bv1, bv1, bv1};
      }
#pragma unroll
      for (int kt = 0; kt < 6; ++kt) {
        bf16x8 w0 = *(const bf16x8*)(wv0 + kt * 32);
        bf16x8 w1 = *(const bf16x8*)(wv1 + kt * 32);
#pragma unroll
        for (int tt = 0; tt < 4; ++tt) {
          bf16x8 xf = XF(tt, kt);
          acc[tt][0] = MFMA16(xf, w0, acc[tt][0], 0, 0, 0);
          acc[tt][1] = MFMA16(xf, w1, acc[tt][1], 0, 0, 0);
        }
      }
#pragma unroll
      for (int dt = 0; dt < 2; ++dt)
#pragma unroll
        for (int kh = 0; kh < 2; ++kh) {
          va[dt][kh] = xpose(acc[2 * kh][dt], acc[2 * kh + 1][dt]);
          *(bf16x8*)(ew + (dt * 2 + kh) * 1024) = va[dt][kh];
        }
    }
  }
  __syncthreads();
  {
    const char* er = exch + hl * 8192 + (half ^ 1) * 4096 + lane * 16;
    if (half == 0) {
#pragma unroll
      for (int f = 0; f < 4; ++f) va[f >> 1][f & 1] = *(const bf16x8*)(er + f * 1024);
    } else {
#pragma unroll
      for (int f = 0; f < 4; ++f) ka[f] = *(const bf16x8*)(er + f * 1024);
    }
  }

  // ---------- S = K @ Q^T with bias as C operand; softmax; P frags ----------
  bf16x8 pbf[2][2];
  float linv[2];
  {
    const f32x4* bias4 = (const f32x4*)biasar + (size_t)(head * 16 + half * 2) * 64 + lane;
    f32x4 s[4][2];
#pragma unroll
    for (int mt = 0; mt < 4; ++mt)
#pragma unroll
      for (int n2 = 0; n2 < 2; ++n2)
        s[mt][n2] = MFMA16(ka[mt], qb[n2], bias4[(mt * 4 + n2) * 64], 0, 0, 0);
#pragma unroll
    for (int n2 = 0; n2 < 2; ++n2) {
      float mx = fmaxf(fmaxf(fmaxf(s[0][n2][0], s[0][n2][1]), fmaxf(s[0][n2][2], s[0][n2][3])),
                       fmaxf(fmaxf(s[1][n2][0], s[1][n2][1]), fmaxf(s[1][n2][2], s[1][n2][3])));
      mx = fmaxf(mx, fmaxf(fmaxf(fmaxf(s[2][n2][0], s[2][n2][1]), fmaxf(s[2][n2][2], s[2][n2][3])),
                           fmaxf(fmaxf(s[3][n2][0], s[3][n2][1]), fmaxf(s[3][n2][2], s[3][n2][3]))));
      mx = fmaxf(mx, __shfl_xor(mx, 16));
      mx = fmaxf(mx, __shfl_xor(mx, 32));
      float sum = 0.0f;
#pragma unroll
      for (int mt = 0; mt < 4; ++mt)
#pragma unroll
        for (int r = 0; r < 4; ++r) {
          float e = __expf(s[mt][n2][r] - mx);
          s[mt][n2][r] = e;
          sum += e;
        }
      sum += __shfl_xor(sum, 16);
      sum += __shfl_xor(sum, 32);
      linv[n2] = 1.0f / sum;
    }
#pragma unroll
    for (int n2 = 0; n2 < 2; ++n2) {
      pbf[0][n2] = xpose(s[0][n2], s[1][n2]);
      pbf[1][n2] = xpose(s[2][n2], s[3][n2]);
    }
  }

  // ---------- O^T = V^T @ P^T, scale, dump frags ----------
  f32x4 o[2][2];
#pragma unroll
  for (int dt = 0; dt < 2; ++dt)
#pragma unroll
    for (int n2 = 0; n2 < 2; ++n2) o[dt][n2] = (f32x4)0.0f;
#pragma unroll
  for (int mh = 0; mh < 2; ++mh)
#pragma unroll
    for (int n2 = 0; n2 < 2; ++n2)
#pragma unroll
      for (int dt = 0; dt < 2; ++dt) o[dt][n2] = MFMA16(va[dt][mh], pbf[mh][n2], o[dt][n2], 0, 0, 0);

  uint2* dst = (uint2*)osout + ((size_t)((b * 6 + head) * 2 + half) * 4) * 64 + lane;
#pragma unroll
  for (int dt = 0; dt < 2; ++dt)
#pragma unroll
    for (int n2 = 0; n2 < 2; ++n2) {
#pragma unroll
      for (int r = 0; r < 4; ++r) o[dt][n2][r] *= linv[n2];
      dst[(dt * 2 + n2) * 64] = pk4(o[dt][n2]);
    }
}

// proj: block = 1 window (64 tokens), 4 waves; wave w covers f in [w*48, w*48+48).
__global__ void __launch_bounds__(256, 4) proj_kernel(
    const unsigned short* __restrict__ osin, const unsigned short* __restrict__ wproj,
    const float* __restrict__ proj_b, float* __restrict__ out) {
  __shared__ __align__(16) char smem[24576];
  const int b = blockIdx.x;
  const int tid = threadIdx.x;
  const int w = tid >> 6;  // 0..3
  const int lane = tid & 63;
  const int g = lane >> 4;
  const int c = lane & 15;

  // ---------- decode frag dump -> [tok][d] swizzled LDS ----------
  {
    const uint2* src = (const uint2*)osin + (size_t)b * 3072;
#pragma unroll
    for (int it = 0; it < 12; ++it) {
      int i = tid + it * 256;
      int ls = i & 63;
      int f = (i >> 6) & 3;  // dt*2 + n2
      int unit = i >> 8;     // head*2 + half
      int head = unit >> 1, half = unit & 1;
      int dt = f >> 1, n2 = f & 1;
      int tok = half * 32 + n2 * 16 + (ls & 15);
      int d0 = head * 32 + dt * 16 + 4 * (ls >> 4);
      uint2 v = src[i];
      *(uint2*)(smem + tok * 384 + (((d0 >> 3) ^ (tok & 7)) << 4) + (d0 & 7) * 2) = v;
    }
  }
  __syncthreads();

  // ---------- GEMM: out = Os @ wproj^T + b ----------
  f32x4 acc[4][3];
#pragma unroll
  for (int mt = 0; mt < 4; ++mt)
#pragma unroll
    for (int ft = 0; ft < 3; ++ft) acc[mt][ft] = (f32x4)0.0f;
#pragma unroll
  for (int kt = 0; kt < 6; ++kt) {
    bf16x8 wf[3];
#pragma unroll
    for (int ft = 0; ft < 3; ++ft)
      wf[ft] = *(const bf16x8*)(wproj + (size_t)(w * 48 + ft * 16 + c) * 192 + kt * 32 + 8 * g);
#pragma unroll
    for (int mt = 0; mt < 4; ++mt) {
      bf16x8 of = *(const bf16x8*)(smem + (mt * 16 + c) * 384 + (((kt * 4 + g) ^ (c & 7)) << 4));
#pragma unroll
      for (int ft = 0; ft < 3; ++ft) acc[mt][ft] = MFMA16(of, wf[ft], acc[mt][ft], 0, 0, 0);
    }
  }
  float* outb = out + (size_t)b * 12288;
#pragma unroll
  for (int ft = 0; ft < 3; ++ft) {
    float pbv = proj_b[w * 48 + ft * 16 + c];
#pragma unroll
    for (int mt = 0; mt < 4; ++mt)
#pragma unroll
      for (int r = 0; r < 4; ++r)
        outb[(mt * 16 + 4 * g + r) * 192 + w * 48 + ft * 16 + c] = acc[mt][ft][r] + pbv;
  }
}

// ===================== FUSED FALLBACK (R4, known-good 323us) =====================
#define XFRAGOLD(tt, kt) \
  (*(const bf16x8*)(xs + ((tt) * 16 + c) * 384 + ((((kt) * 4 + g) ^ (c & 7)) << 4)))

__global__ void __launch_bounds__(384, 3) win_attn(
    const float* __restrict__ x, const unsigned short* __restrict__ wqkv,
    const unsigned short* __restrict__ wproj, const float* __restrict__ biasar,
    const float* __restrict__ bq, const float* __restrict__ proj_b, float* __restrict__ out) {
  __shared__ __align__(16) char smem[24576];
  const int b = blockIdx.x;
  const int tid = threadIdx.x;
  const int w = tid >> 6;
  const int lane = tid & 63;
  const int g = lane >> 4;
  const int c = lane & 15;
  char* xs = smem;

  {
    const float* xb = x + (size_t)b * 12288;
#pragma unroll
    for (int it = 0; it < 8; ++it) {
      int idx = tid + it * 384;
      int tok = idx / 48, c4 = idx % 48;
      float4 v = *(const float4*)(xb + tok * 192 + c4 * 4);
      *(uint2*)(xs + tok * 384 + (((c4 >> 1) ^ (tok & 7)) << 4) + (c4 & 1) * 8) =
          make_uint2(pk2(v.x, v.y), pk2(v.z, v.w));
    }
  }
  __syncthreads();

  bf16x8 qb[4];
  {
    f32x4 acc[2][4];
#pragma unroll
    for (int dt = 0; dt < 2; ++dt)
#pragma unroll
      for (int tt = 0; tt < 4; ++tt) acc[dt][tt] = (f32x4)0.0f;
#pragma unroll
    for (int kt = 0; kt < 6; ++kt) {
      bf16x8 wf[2];
#pragma unroll
      for (int dt = 0; dt < 2; ++dt)
        wf[dt] = *(const bf16x8*)(wqkv + (size_t)(w * 32 + dt * 16 + c) * 192 + kt * 32 + 8 * g);
#pragma unroll
      for (int tt = 0; tt < 4; ++tt) {
        bf16x8 xf = XFRAGOLD(tt, kt);
#pragma unroll
        for (int dt = 0; dt < 2; ++dt) acc[dt][tt] = MFMA16(wf[dt], xf, acc[dt][tt], 0, 0, 0);
      }
    }
#pragma unroll
    for (int dt = 0; dt < 2; ++dt)
#pragma unroll
      for (int r = 0; r < 4; ++r) {
        float bv = bq[w * 32 + dt * 16 + 4 * g + r];
#pragma unroll
        for (int tt = 0; tt < 4; ++tt) acc[dt][tt][r] += bv;
      }
#pragma unroll
    for (int nt = 0; nt < 4; ++nt) qb[nt] = xpose(acc[0][nt], acc[1][nt]);
  }

  bf16x8 ka[4];
  {
    f32x4 acc[2][4];
#pragma unroll
    for (int dt = 0; dt < 2; ++dt)
#pragma unroll
      for (int tt = 0; tt < 4; ++tt) acc[dt][tt] = (f32x4)0.0f;
#pragma unroll
    for (int kt = 0; kt < 6; ++kt) {
      bf16x8 wf[2];
#pragma unroll
      for (int dt = 0; dt < 2; ++dt)
        wf[dt] =
            *(const bf16x8*)(wqkv + (size_t)(192 + w * 32 + dt * 16 + c) * 192 + kt * 32 + 8 * g);
#pragma unroll
      for (int tt = 0; tt < 4; ++tt) {
        bf16x8 xf = XFRAGOLD(tt, kt);
#pragma unroll
        for (int dt = 0; dt < 2; ++dt) acc[dt][tt] = MFMA16(wf[dt], xf, acc[dt][tt], 0, 0, 0);
      }
    }
#pragma unroll
    for (int dt = 0; dt < 2; ++dt)
#pragma unroll
      for (int r = 0; r < 4; ++r) {
        float bv = bq[192 + w * 32 + dt * 16 + 4 * g + r];
#pragma unroll
        for (int tt = 0; tt < 4; ++tt) acc[dt][tt][r] += bv;
      }
#pragma unroll
    for (int mt = 0; mt < 4; ++mt) ka[mt] = xpose(acc[0][mt], acc[1][mt]);
  }

  bf16x8 pbf[2][4];
  float linv[4];
  const f32x4* bias4 = (const f32x4*)biasar;
#pragma unroll
  for (int h = 0; h < 2; ++h) {
    f32x4 s[4][2];
#pragma unroll
    for (int mt = 0; mt < 4; ++mt)
#pragma unroll
      for (int n2 = 0; n2 < 2; ++n2) {
        int nt = h * 2 + n2;
        f32x4 t = MFMA16(ka[mt], qb[nt], (f32x4)0.0f, 0, 0, 0);
        s[mt][n2] = t + bias4[(w * 16 + mt * 4 + nt) * 64 + lane];
      }
#pragma unroll
    for (int n2 = 0; n2 < 2; ++n2) {
      int nt = h * 2 + n2;
      float mx = -1e30f;
#pragma unroll
      for (int mt = 0; mt < 4; ++mt)
#pragma unroll
        for (int r = 0; r < 4; ++r) mx = fmaxf(mx, s[mt][n2][r]);
      mx = fmaxf(mx, __shfl_xor(mx, 16));
      mx = fmaxf(mx, __shfl_xor(mx, 32));
      float sum = 0.0f;
#pragma unroll
      for (int mt = 0; mt < 4; ++mt)
#pragma unroll
        for (int r = 0; r < 4; ++r) {
          float e = __expf(s[mt][n2][r] - mx);
          s[mt][n2][r] = e;
          sum += e;
        }
      sum += __shfl_xor(sum, 16);
      sum += __shfl_xor(sum, 32);
      linv[nt] = 1.0f / sum;
    }
#pragma unroll
    for (int n2 = 0; n2 < 2; ++n2) {
      pbf[0][h * 2 + n2] = xpose(s[0][n2], s[1][n2]);
      pbf[1][h * 2 + n2] = xpose(s[2][n2], s[3][n2]);
    }
  }

  bf16x8 va[2][2];
  {
    f32x4 acc[4][2];
#pragma unroll
    for (int mt = 0; mt < 4; ++mt)
#pragma unroll
      for (int dt = 0; dt < 2; ++dt) acc[mt][dt] = (f32x4)0.0f;
#pragma unroll
    for (int kt = 0; kt < 6; ++kt) {
      bf16x8 wf[2];
#pragma unroll
      for (int dt = 0; dt < 2; ++dt)
        wf[dt] =
            *(const bf16x8*)(wqkv + (size_t)(384 + w * 32 + dt * 16 + c) * 192 + kt * 32 + 8 * g);
#pragma unroll
      for (int tt = 0; tt < 4; ++tt) {
        bf16x8 xf = XFRAGOLD(tt, kt);
#pragma unroll
        for (int dt = 0; dt < 2; ++dt) acc[tt][dt] = MFMA16(xf, wf[dt], acc[tt][dt], 0, 0, 0);
      }
    }
#pragma unroll
    for (int dt = 0; dt < 2; ++dt) {
      float bv = bq[384 + w * 32 + dt * 16 + c];
#pragma unroll
      for (int mt = 0; mt < 4; ++mt)
#pragma unroll
        for (int r = 0; r < 4; ++r) acc[mt][dt][r] += bv;
    }
#pragma unroll
    for (int dt = 0; dt < 2; ++dt)
#pragma unroll
      for (int kh = 0; kh < 2; ++kh) va[dt][kh] = xpose(acc[2 * kh][dt], acc[2 * kh + 1][dt]);
  }

  f32x4 o[2][4];
#pragma unroll
  for (int dt = 0; dt < 2; ++dt)
#pragma unroll
    for (int nt = 0; nt < 4; ++nt) o[dt][nt] = (f32x4)0.0f;
#pragma unroll
  for (int mh = 0; mh < 2; ++mh)
#pragma unroll
    for (int nt = 0; nt < 4; ++nt)
#pragma unroll
      for (int dt = 0; dt < 2; ++dt) o[dt][nt] = MFMA16(va[dt][mh], pbf[mh][nt], o[dt][nt], 0, 0, 0);
#pragma unroll
  for (int dt = 0; dt < 2; ++dt)
#pragma unroll
    for (int nt = 0; nt < 4; ++nt)
#pragma unroll
      for (int r = 0; r < 4; ++r) o[dt][nt][r] *= linv[nt];

  __syncthreads();
#pragma unroll
  for (int dt = 0; dt < 2; ++dt)
#pragma unroll
    for (int nt = 0; nt < 4; ++nt)
      *(uint2*)(xs + (nt * 16 + c) * 384 + (((w * 4 + dt * 2 + (g >> 1)) ^ (c & 7)) << 4) +
                (g & 1) * 8) =
          make_uint2(pk2(o[dt][nt][0], o[dt][nt][1]), pk2(o[dt][nt][2], o[dt][nt][3]));
  __syncthreads();

  f32x4 accP[4][2];
#pragma unroll
  for (int mt = 0; mt < 4; ++mt)
#pragma unroll
    for (int ft = 0; ft < 2; ++ft) accP[mt][ft] = (f32x4)0.0f;
#pragma unroll
  for (int kt = 0; kt < 6; ++kt) {
    bf16x8 wp[2];
#pragma unroll
    for (int ft = 0; ft < 2; ++ft)
      wp[ft] = *(const bf16x8*)(wproj + (size_t)(w * 32 + ft * 16 + c) * 192 + kt * 32 + 8 * g);
#pragma unroll
    for (int mt = 0; mt < 4; ++mt) {
      bf16x8 of = *(const bf16x8*)(xs + (mt * 16 + c) * 384 + (((kt * 4 + g) ^ (c & 7)) << 4));
#pragma unroll
      for (int ft = 0; ft < 2; ++ft) accP[mt][ft] = MFMA16(of, wp[ft], accP[mt][ft], 0, 0, 0);
    }
  }
  float pb0 = proj_b[w * 32 + c];
  float pb1 = proj_b[w * 32 + 16 + c];
  float* outb = out + (size_t)b * 12288;
#pragma unroll
  for (int mt = 0; mt < 4; ++mt)
#pragma unroll
    for (int ft = 0; ft < 2; ++ft) {
      float pbv = ft ? pb1 : pb0;
#pragma unroll
      for (int r = 0; r < 4; ++r)
        outb[(mt * 16 + 4 * g + r) * 192 + w * 32 + ft * 16 + c] = accP[mt][ft][r] + pbv;
    }
}

extern "C" void kernel_launch(void* const* d_in, const int* in_sizes, int n_in,
                              void* d_out, int out_size, void* d_ws, size_t ws_size,
                              hipStream_t stream) {
  const float* x = (const float*)d_in[0];
  const float* qkv_w = (const float*)d_in[1];
  const float* qkv_b = (const float*)d_in[2];
  const float* proj_w = (const float*)d_in[3];
  const float* proj_b = (const float*)d_in[4];
  const float* rpb = (const float*)d_in[5];
  char* ws = (char*)d_ws;
  unsigned short* wqkv = (unsigned short*)ws;
  unsigned short* wproj = (unsigned short*)(ws + 221184);
  float* biasar = (float*)(ws + 294912);
  float* bqv = (float*)(ws + 393216);

  prep_kernel<<<432, 256, 0, stream>>>(qkv_w, qkv_b, proj_w, rpb, wqkv, wproj, biasar, bqv);

  if (ws_size >= (size_t)WS_NEED) {
    unsigned short* osbuf = (unsigned short*)(ws + OS_OFF);
    win_attn6<<<8192, 384, 0, stream>>>(x, wqkv, biasar, bqv, osbuf);
    proj_kernel<<<4096, 256, 0, stream>>>(osbuf, wproj, proj_b, (float*)d_out);
  } else {
    win_attn<<<4096, 384, 0, stream>>>(x, wqkv, wproj, biasar, bqv, proj_b, (float*)d_out);
  }
}